// Round 2
// baseline (1759.058 us; speedup 1.0000x reference)
//
#include <hip/hip_runtime.h>
#include <math.h>

#define N_NODES 50000
#define N_EDGES 800000
#define EGRID 256          // persistent blocks, 1 per CU (LDS-capped)
#define EGROUPS 6250       // 800000 / 128 edges per group

// fp32 = a0+a1+a2 (3 bf16 terms). 6 MFMA term-pairs per product -> fp32-class
// numerics on the bf16 matrix core (~2^-24 relative with trunc-split).
typedef __attribute__((ext_vector_type(8))) short short8_t;   // bf16x8 (4 VGPR)
typedef __attribute__((ext_vector_type(4))) float float4_t;   // fp32x4 acc

union U8 { short8_t v; unsigned short u[8]; };

__device__ __forceinline__ unsigned short bf16_rn(float f) {
    unsigned u = __float_as_uint(f);
    u += 0x7fffu + ((u >> 16) & 1u);
    return (unsigned short)(u >> 16);
}
__device__ __forceinline__ float bf2f(unsigned short h) {
    return __uint_as_float((unsigned)h << 16);
}
// round-to-nearest split (prep only; max precision for reused weights)
__device__ __forceinline__ void split3(float f, unsigned short& s0,
                                       unsigned short& s1, unsigned short& s2) {
    s0 = bf16_rn(f);  float r = f - bf2f(s0);
    s1 = bf16_rn(r);  r -= bf2f(s1);
    s2 = bf16_rn(r);
}
// truncation split (hot kernels): trunc/sub are EXACT, only s2 rounds.
__device__ __forceinline__ void split3t(float f, unsigned short& s0,
                                        unsigned short& s1, unsigned short& s2) {
    unsigned u = __float_as_uint(f);
    s0 = (unsigned short)(u >> 16);
    float r = f - bf2f(s0);            // exact
    unsigned v = __float_as_uint(r);
    s1 = (unsigned short)(v >> 16);
    float r2 = r - bf2f(s1);           // exact
    s2 = bf16_rn(r2);
}

// ---------------------------------------------------------------------------
// ws layout (bytes):
//   BTn0/1/2 [256][128] bf16 : rows 0..127 = F1^T (P), 128..255 = F2^T (Q,x)
//   BTg0/1/2 [128][128] bf16 : F3^T (Q,g)
//   BTw_t    147456 B       : [vp_W1|pol_W1]^T 3-split, TILED for LDS:
//                             [kc4][ntl12][arr3][lane64][e8] bf16 — the edge
//                             kernel copies it verbatim to LDS and reads
//                             tile_base + lane*16 (conflict-free, linear).
//   cb[128] folded bias (into P), b1c[192], W2c[192], flags[16]
//   P[50000*128] = x@F1 + cb ; Q[50000*128] = x@F2 + g@F3
// ---------------------------------------------------------------------------

__global__ __launch_bounds__(256) void prep_kernel(
    const float* __restrict__ node_W, const float* __restrict__ node_b,
    const float* __restrict__ nbr_W,  const float* __restrict__ nbr_b,
    const float* __restrict__ gud_W,  const float* __restrict__ gud_b,
    const float* __restrict__ enc_W,  const float* __restrict__ enc_b,
    const float* __restrict__ vp_W1,  const float* __restrict__ vp_b1,
    const float* __restrict__ vp_W2,  const float* __restrict__ pol_W1,
    const float* __restrict__ pol_b1, const float* __restrict__ pol_W2,
    unsigned short* __restrict__ BTn0, unsigned short* __restrict__ BTn1,
    unsigned short* __restrict__ BTn2,
    unsigned short* __restrict__ BTg0, unsigned short* __restrict__ BTg1,
    unsigned short* __restrict__ BTg2,
    unsigned short* __restrict__ BTw_t,
    float* __restrict__ cb, float* __restrict__ b1c, float* __restrict__ W2c,
    int* __restrict__ flags)
{
    const int k = blockIdx.x;   // input channel 0..127
    const int j = threadIdx.x;  // output channel
    if (j < 128) {
        float a = 0.f, b = 0.f;
        #pragma unroll 4
        for (int m = 0; m < 128; ++m) {
            a = fmaf(node_W[k * 128 + m], enc_W[m * 128 + j], a);
            b = fmaf(gud_W [k * 128 + m], enc_W[(256 + m) * 128 + j], b);
        }
        size_t i1 = (size_t)j * 128 + k;          // B^T[n=j][k]
        split3(a, BTn0[i1], BTn1[i1], BTn2[i1]);
        split3(b, BTg0[i1], BTg1[i1], BTg2[i1]);
    } else {
        const int n = j - 128;
        float a = 0.f;
        #pragma unroll 4
        for (int m = 0; m < 128; ++m)
            a = fmaf(nbr_W[k * 128 + m], enc_W[(128 + m) * 128 + n], a);
        size_t i2 = (size_t)(128 + n) * 128 + k;  // B^T[n=128+n][k]
        split3(a, BTn0[i2], BTn1[i2], BTn2[i2]);
    }
    if (j < 192) {
        float wv = (j < 64) ? vp_W1[k * 64 + j] : pol_W1[k * 128 + (j - 64)];
        // tiled index: (kc, ntl, arr, qq*16+ii, e)
        const int kc = k >> 5, qq = (k >> 3) & 3, e = k & 7;
        const int ntl = j >> 4, ii = j & 15;
        size_t bidx = (size_t)((kc * 12 + ntl) * 3) * 512
                    + (size_t)(qq * 16 + ii) * 8 + e;
        split3(wv, BTw_t[bidx], BTw_t[bidx + 512], BTw_t[bidx + 1024]);
    }
    if (k == 0) {
        if (j < 128) {
            float cc = enc_b[j];
            for (int m = 0; m < 128; ++m) {
                cc = fmaf(node_b[m], enc_W[m * 128 + j], cc);
                cc = fmaf(nbr_b [m], enc_W[(128 + m) * 128 + j], cc);
                cc = fmaf(gud_b [m], enc_W[(256 + m) * 128 + j], cc);
            }
            cb[j] = cc;
        }
        if (j < 192) {
            b1c[j] = (j < 64) ? vp_b1[j] : pol_b1[j - 64];
            W2c[j] = (j < 64) ? vp_W2[j] : pol_W2[j - 64];
        }
        // --- runtime C/D orientation probe (wave 0), verified round 5 ---
        if (j < 64) {
            const int l = j, li = l & 15, lq = l >> 4;
            U8 A, B;
            #pragma unroll
            for (int u = 0; u < 8; ++u) { A.u[u] = 0; B.u[u] = 0; }
            if (lq == 0) {
                A.u[0] = bf16_rn((float)(li + 1));
                A.u[1] = bf16_rn(1.0f);
                B.u[0] = bf16_rn(1.0f);
                B.u[1] = bf16_rn((float)(100 * (li + 1)));
            }
            float4_t d = (float4_t){0.f, 0.f, 0.f, 0.f};
            d = __builtin_amdgcn_mfma_f32_16x16x32_bf16(A.v, B.v, d, 0, 0, 0);
            if (l == 17) {
                flags[0] = (fabsf(d[2] - 702.f) < 1.0f) ? 1 : 0;
            }
        }
    }
}

// ---------------------------------------------------------------------------
// node_kernel: unchanged from round 0 (64 nodes/block).
// ---------------------------------------------------------------------------
__global__ __launch_bounds__(256, 3) void node_kernel(
    const float* __restrict__ x, const float* __restrict__ g,
    const unsigned short* __restrict__ BTn0, const unsigned short* __restrict__ BTn1,
    const unsigned short* __restrict__ BTn2,
    const unsigned short* __restrict__ BTg0, const unsigned short* __restrict__ BTg1,
    const unsigned short* __restrict__ BTg2,
    const float* __restrict__ cb, const int* __restrict__ flags,
    float* __restrict__ P, float* __restrict__ Q)
{
    __shared__ unsigned short a0s[4 * 64 * 8];   // [k-sub][node][8]
    __shared__ unsigned short a1s[4 * 64 * 8];
    __shared__ unsigned short a2s[4 * 64 * 8];
    const int t = threadIdx.x;
    const int w = t >> 6, lane = t & 63;
    const int i16 = lane & 15, q = lane >> 4;
    const int base = blockIdx.x * 64;
    const int swap = flags[0];
    const int el = t >> 2, hh = t & 3;
    int nodeL = base + el; if (nodeL > N_NODES - 1) nodeL = N_NODES - 1;
    const float* xrow = x + (size_t)nodeL * 128 + hh * 8;
    const float* grow = g + (size_t)nodeL * 128 + hh * 8;

    float4_t acc[4][4];
    #pragma unroll
    for (int mt = 0; mt < 4; ++mt)
        #pragma unroll
        for (int nt = 0; nt < 4; ++nt) acc[mt][nt] = (float4_t){0.f, 0.f, 0.f, 0.f};

    float4 pv0 = *(const float4*)(xrow);
    float4 pv1 = *(const float4*)(xrow + 4);

    for (int kc = 0; kc < 8; ++kc) {
        U8 s0, s1, s2;
        {
            float e[8] = {pv0.x, pv0.y, pv0.z, pv0.w, pv1.x, pv1.y, pv1.z, pv1.w};
            #pragma unroll
            for (int u = 0; u < 8; ++u) split3t(e[u], s0.u[u], s1.u[u], s2.u[u]);
        }
        __syncthreads();
        {
            size_t off = ((size_t)hh * 64 + el) * 8;
            *(short8_t*)(a0s + off) = s0.v;
            *(short8_t*)(a1s + off) = s1.v;
            *(short8_t*)(a2s + off) = s2.v;
        }
        __syncthreads();
        if (kc < 7) {
            const float* nsrc = (kc + 1 < 4) ? (xrow + (kc + 1) * 32)
                                             : (grow + (kc + 1 - 4) * 32);
            pv0 = *(const float4*)(nsrc);
            pv1 = *(const float4*)(nsrc + 4);
        }
        if (kc < 4) {
            short8_t b0[4], b1v[4], b2v[4];
            #pragma unroll
            for (int ntl = 0; ntl < 4; ++ntl) {
                int ntg = w + ntl * 4;
                size_t roff = ((size_t)(ntg * 16 + i16)) * 128 + kc * 32 + q * 8;
                b0[ntl]  = *(const short8_t*)(BTn0 + roff);
                b1v[ntl] = *(const short8_t*)(BTn1 + roff);
                b2v[ntl] = *(const short8_t*)(BTn2 + roff);
            }
            #pragma unroll
            for (int mt = 0; mt < 4; ++mt) {
                size_t aoff = ((size_t)q * 64 + mt * 16 + i16) * 8;
                short8_t a0 = *(const short8_t*)(a0s + aoff);
                short8_t a1 = *(const short8_t*)(a1s + aoff);
                short8_t a2 = *(const short8_t*)(a2s + aoff);
                #pragma unroll
                for (int ntl = 0; ntl < 4; ++ntl) {
                    float4_t c = acc[mt][ntl];
                    c = __builtin_amdgcn_mfma_f32_16x16x32_bf16(a0, b0[ntl],  c, 0, 0, 0);
                    c = __builtin_amdgcn_mfma_f32_16x16x32_bf16(a0, b1v[ntl], c, 0, 0, 0);
                    c = __builtin_amdgcn_mfma_f32_16x16x32_bf16(a1, b0[ntl],  c, 0, 0, 0);
                    c = __builtin_amdgcn_mfma_f32_16x16x32_bf16(a0, b2v[ntl], c, 0, 0, 0);
                    c = __builtin_amdgcn_mfma_f32_16x16x32_bf16(a1, b1v[ntl], c, 0, 0, 0);
                    c = __builtin_amdgcn_mfma_f32_16x16x32_bf16(a2, b0[ntl],  c, 0, 0, 0);
                    acc[mt][ntl] = c;
                }
            }
        } else {
            short8_t b0[2], b1v[2], b2v[2];
            #pragma unroll
            for (int ntl = 0; ntl < 2; ++ntl) {
                int ntg = w + (ntl + 2) * 4;   // Q tiles w+8, w+12
                size_t roff = ((size_t)((ntg - 8) * 16 + i16)) * 128 + (kc - 4) * 32 + q * 8;
                b0[ntl]  = *(const short8_t*)(BTg0 + roff);
                b1v[ntl] = *(const short8_t*)(BTg1 + roff);
                b2v[ntl] = *(const short8_t*)(BTg2 + roff);
            }
            #pragma unroll
            for (int mt = 0; mt < 4; ++mt) {
                size_t aoff = ((size_t)q * 64 + mt * 16 + i16) * 8;
                short8_t a0 = *(const short8_t*)(a0s + aoff);
                short8_t a1 = *(const short8_t*)(a1s + aoff);
                short8_t a2 = *(const short8_t*)(a2s + aoff);
                #pragma unroll
                for (int ntl = 0; ntl < 2; ++ntl) {
                    float4_t c = acc[mt][ntl + 2];
                    c = __builtin_amdgcn_mfma_f32_16x16x32_bf16(a0, b0[ntl],  c, 0, 0, 0);
                    c = __builtin_amdgcn_mfma_f32_16x16x32_bf16(a0, b1v[ntl], c, 0, 0, 0);
                    c = __builtin_amdgcn_mfma_f32_16x16x32_bf16(a1, b0[ntl],  c, 0, 0, 0);
                    c = __builtin_amdgcn_mfma_f32_16x16x32_bf16(a0, b2v[ntl], c, 0, 0, 0);
                    c = __builtin_amdgcn_mfma_f32_16x16x32_bf16(a1, b1v[ntl], c, 0, 0, 0);
                    c = __builtin_amdgcn_mfma_f32_16x16x32_bf16(a2, b0[ntl],  c, 0, 0, 0);
                    acc[mt][ntl + 2] = c;
                }
            }
        }
    }

    if (!swap) {
        #pragma unroll
        for (int mt = 0; mt < 4; ++mt)
            #pragma unroll
            for (int ntl = 0; ntl < 4; ++ntl) {
                int ntg = w + ntl * 4;
                int chan = ntg * 16 + i16;
                bool isP = (ntg < 8);
                float bias = isP ? cb[chan] : 0.f;
                #pragma unroll
                for (int r = 0; r < 4; ++r) {
                    int node = base + mt * 16 + q * 4 + r;
                    if (node < N_NODES) {
                        if (isP) P[(size_t)node * 128 + chan] = acc[mt][ntl][r] + bias;
                        else     Q[(size_t)node * 128 + (chan - 128)] = acc[mt][ntl][r];
                    }
                }
            }
    } else {
        #pragma unroll
        for (int mt = 0; mt < 4; ++mt) {
            int node = base + mt * 16 + i16;
            if (node < N_NODES) {
                #pragma unroll
                for (int ntl = 0; ntl < 4; ++ntl) {
                    int ntg = w + ntl * 4;
                    int chanb = ntg * 16 + q * 4;
                    bool isP = (ntg < 8);
                    float4 vv;
                    vv.x = acc[mt][ntl][0] + (isP ? cb[chanb + 0] : 0.f);
                    vv.y = acc[mt][ntl][1] + (isP ? cb[chanb + 1] : 0.f);
                    vv.z = acc[mt][ntl][2] + (isP ? cb[chanb + 2] : 0.f);
                    vv.w = acc[mt][ntl][3] + (isP ? cb[chanb + 3] : 0.f);
                    if (isP) *(float4*)(P + (size_t)node * 128 + chanb) = vv;
                    else     *(float4*)(Q + (size_t)node * 128 + chanb - 128) = vv;
                }
            }
        }
    }
}

// ---------------------------------------------------------------------------
// edge_kernel (round 2 rewrite): M-SPLIT persistent kernel.
//   - 256 persistent blocks x 512 threads (8 waves). Each wave owns 16 edges
//     per group; all 12 N-tiles. Group = 128 edges; grid-stride over 6250.
//   - B ([vp_W1|pol_W1]^T 3-split, 147456 B) lives ENTIRELY in LDS, loaded
//     once per block. ds_read addr = tile_base + lane*16 -> conflict-free.
//   - A-operand is lane-private: lane (i16,q) gathers P/Q channels q*8..+7
//     of edge eg+i16 directly (the exact A-frag slots), relu+split3t in reg.
//     ZERO LDS round-trip, ZERO __syncthreads in the steady-state loop.
//   - Epilogue is wave-local (all 192 N-channels of an edge in one wave):
//     shfl reduce, no cross-wave LDS combine.
//   Rationale: round 1 showed occupancy is not the limiter; the per-kc
//   barrier + LDS round-trip structure was. This removes it.
// ---------------------------------------------------------------------------
#define MFMA_PHASE(C)                                                           \
    {                                                                           \
        _Pragma("unroll")                                                       \
        for (int n = 0; n < 12; ++n) {                                          \
            const unsigned short* bp = Bl + ((C) * 12 + n) * 1536 + lane * 8;   \
            short8_t b0  = *(const short8_t*)(bp);                              \
            short8_t b1v = *(const short8_t*)(bp + 512);                        \
            short8_t b2v = *(const short8_t*)(bp + 1024);                       \
            float4_t cc = acc[n];                                               \
            cc = __builtin_amdgcn_mfma_f32_16x16x32_bf16(a0.v, b0,  cc, 0, 0, 0); \
            cc = __builtin_amdgcn_mfma_f32_16x16x32_bf16(a0.v, b1v, cc, 0, 0, 0); \
            cc = __builtin_amdgcn_mfma_f32_16x16x32_bf16(a1.v, b0,  cc, 0, 0, 0); \
            cc = __builtin_amdgcn_mfma_f32_16x16x32_bf16(a0.v, b2v, cc, 0, 0, 0); \
            cc = __builtin_amdgcn_mfma_f32_16x16x32_bf16(a1.v, b1v, cc, 0, 0, 0); \
            cc = __builtin_amdgcn_mfma_f32_16x16x32_bf16(a2.v, b0,  cc, 0, 0, 0); \
            acc[n] = cc;                                                        \
        }                                                                       \
    }

#define MAKE_FRAGS(P0, P1, Q0, Q1)                                              \
    {                                                                           \
        float ev[8] = {fmaxf((P0).x + (Q0).x, 0.f), fmaxf((P0).y + (Q0).y, 0.f),\
                       fmaxf((P0).z + (Q0).z, 0.f), fmaxf((P0).w + (Q0).w, 0.f),\
                       fmaxf((P1).x + (Q1).x, 0.f), fmaxf((P1).y + (Q1).y, 0.f),\
                       fmaxf((P1).z + (Q1).z, 0.f), fmaxf((P1).w + (Q1).w, 0.f)};\
        _Pragma("unroll")                                                       \
        for (int u = 0; u < 8; ++u) split3t(ev[u], a0.u[u], a1.u[u], a2.u[u]);  \
    }

__global__ __launch_bounds__(512, 2) void edge_kernel(
    const int* __restrict__ ei,
    const float* __restrict__ P, const float* __restrict__ Q,
    const unsigned short* __restrict__ BTw_t,
    const float* __restrict__ b1c, const float* __restrict__ W2c,
    const float* __restrict__ vp_b2, const float* __restrict__ pol_b2,
    const int* __restrict__ flags,
    float* __restrict__ out)
{
    extern __shared__ unsigned short Bl[];   // 73728 shorts = 147456 B

    const int t = threadIdx.x;
    const int w = t >> 6, lane = t & 63;
    const int i16 = lane & 15, q = lane >> 4;
    const int swap = flags[0];

    // ---- one-time: copy tiled B into LDS (coalesced, linear) ----
    #pragma unroll
    for (int i = 0; i < 18; ++i) {
        int idx = (i * 512 + t) * 8;
        *(short8_t*)(Bl + idx) = *(const short8_t*)(BTw_t + idx);
    }
    // per-lane epilogue constants (path A layout: channel n*16+i16)
    float b1r[12], w2r[12];
    #pragma unroll
    for (int n = 0; n < 12; ++n) {
        b1r[n] = b1c[n * 16 + i16];
        w2r[n] = W2c[n * 16 + i16];
    }
    const float vb2 = vp_b2[0], pb2 = pol_b2[0];
    __syncthreads();   // the ONLY barrier; steady state below is barrier-free

    if (blockIdx.x == 0 && t == 0) out[3 * N_EDGES] = 0.0f;

    // ---- first group's gather setup ----
    int grp = blockIdx.x;
    {
        int eg0 = grp * 128 + w * 16;
        int rowI = ei[eg0 + i16];
        int colI = ei[N_EDGES + eg0 + i16];
        const float* Pp0 = P + (size_t)rowI * 128 + q * 8;
        const float* Qp0 = Q + (size_t)colI * 128 + q * 8;
        // fall through with pointers below
        const float* Pp = Pp0;
        const float* Qp = Qp0;
        float4 pA0 = *(const float4*)(Pp);     float4 pA1 = *(const float4*)(Pp + 4);
        float4 qA0 = *(const float4*)(Qp);     float4 qA1 = *(const float4*)(Qp + 4);
        float4 pB0, pB1, qB0, qB1;

        for (; grp < EGROUPS; grp += EGRID) {
            const int eg = grp * 128 + w * 16;
            float4_t acc[12];
            #pragma unroll
            for (int n = 0; n < 12; ++n) acc[n] = (float4_t){0.f, 0.f, 0.f, 0.f};

            U8 a0, a1, a2;
            const float *Ppn, *Qpn;

            // ---- kc = 0 ----
            pB0 = *(const float4*)(Pp + 32);  pB1 = *(const float4*)(Pp + 36);
            qB0 = *(const float4*)(Qp + 32);  qB1 = *(const float4*)(Qp + 36);
            MAKE_FRAGS(pA0, pA1, qA0, qA1);
            MFMA_PHASE(0);
            // ---- kc = 1 ----
            pA0 = *(const float4*)(Pp + 64);  pA1 = *(const float4*)(Pp + 68);
            qA0 = *(const float4*)(Qp + 64);  qA1 = *(const float4*)(Qp + 68);
            MAKE_FRAGS(pB0, pB1, qB0, qB1);
            MFMA_PHASE(1);
            // ---- kc = 2 (also prefetch next group's edge indices) ----
            pB0 = *(const float4*)(Pp + 96);  pB1 = *(const float4*)(Pp + 100);
            qB0 = *(const float4*)(Qp + 96);  qB1 = *(const float4*)(Qp + 100);
            int gn = grp + EGRID; if (gn >= EGROUPS) gn = grp;
            int egn = gn * 128 + w * 16;
            int nrow = ei[egn + i16];
            int ncol = ei[N_EDGES + egn + i16];
            MAKE_FRAGS(pA0, pA1, qA0, qA1);
            MFMA_PHASE(2);
            // ---- kc = 3 (also prefetch next group's kc0 gathers) ----
            Ppn = P + (size_t)nrow * 128 + q * 8;
            Qpn = Q + (size_t)ncol * 128 + q * 8;
            pA0 = *(const float4*)(Ppn);  pA1 = *(const float4*)(Ppn + 4);
            qA0 = *(const float4*)(Qpn);  qA1 = *(const float4*)(Qpn + 4);
            MAKE_FRAGS(pB0, pB1, qB0, qB1);
            MFMA_PHASE(3);

            // ---- epilogue: wave-local reduce + store ----
            if (!swap) {
                float vs[4] = {0.f, 0.f, 0.f, 0.f}, ps[4] = {0.f, 0.f, 0.f, 0.f};
                #pragma unroll
                for (int n = 0; n < 12; ++n) {
                    float b1s = b1r[n], w2s = w2r[n];
                    #pragma unroll
                    for (int r = 0; r < 4; ++r) {
                        float hv = fmaxf(acc[n][r] + b1s, 0.f) * w2s;
                        if (n < 4) vs[r] += hv; else ps[r] += hv;
                    }
                }
                #pragma unroll
                for (int off = 1; off < 16; off <<= 1)
                    #pragma unroll
                    for (int r = 0; r < 4; ++r) {
                        vs[r] += __shfl_xor(vs[r], off, 64);
                        ps[r] += __shfl_xor(ps[r], off, 64);
                    }
                if (i16 == 0) {
                    #pragma unroll
                    for (int r = 0; r < 4; ++r) {
                        int e = eg + q * 4 + r;
                        float prob = 1.0f / (1.0f + expf(-(ps[r] + pb2)));
                        out[e] = vs[r] + vb2;
                        out[N_EDGES + e] = prob;
                        out[2 * N_EDGES + e] = (prob > 0.5f) ? 1.0f : 0.0f;
                    }
                }
            } else {
                float v = 0.f, p = 0.f;
                #pragma unroll
                for (int n = 0; n < 12; ++n)
                    #pragma unroll
                    for (int r = 0; r < 4; ++r) {
                        int ch = n * 16 + q * 4 + r;
                        float hv = fmaxf(acc[n][r] + b1c[ch], 0.f) * W2c[ch];
                        if (n < 4) v += hv; else p += hv;
                    }
                v += __shfl_xor(v, 16, 64); v += __shfl_xor(v, 32, 64);
                p += __shfl_xor(p, 16, 64); p += __shfl_xor(p, 32, 64);
                if (q == 0) {
                    int e = eg + i16;
                    float prob = 1.0f / (1.0f + expf(-(p + pb2)));
                    out[e] = v + vb2;
                    out[N_EDGES + e] = prob;
                    out[2 * N_EDGES + e] = (prob > 0.5f) ? 1.0f : 0.0f;
                }
            }

            Pp = Ppn;  Qp = Qpn;   // rotate next group's pointers/data in
        }
    }
}

extern "C" void kernel_launch(void* const* d_in, const int* in_sizes, int n_in,
                              void* d_out, int out_size, void* d_ws, size_t ws_size,
                              hipStream_t stream) {
    const float* x      = (const float*)d_in[0];
    const int*   ei     = (const int*)  d_in[1];
    const float* gf     = (const float*)d_in[2];
    const float* node_W = (const float*)d_in[3];
    const float* node_b = (const float*)d_in[4];
    const float* nbr_W  = (const float*)d_in[5];
    const float* nbr_b  = (const float*)d_in[6];
    const float* gud_W  = (const float*)d_in[7];
    const float* gud_b  = (const float*)d_in[8];
    const float* enc_W  = (const float*)d_in[9];
    const float* enc_b  = (const float*)d_in[10];
    const float* vp_W1  = (const float*)d_in[11];
    const float* vp_b1  = (const float*)d_in[12];
    const float* vp_W2  = (const float*)d_in[13];
    const float* vp_b2  = (const float*)d_in[14];
    const float* pol_W1 = (const float*)d_in[15];
    const float* pol_b1 = (const float*)d_in[16];
    const float* pol_W2 = (const float*)d_in[17];
    const float* pol_b2 = (const float*)d_in[18];
    float* out = (float*)d_out;

    unsigned char* wsb = (unsigned char*)d_ws;
    unsigned short* BTn0 = (unsigned short*)(wsb + 0);
    unsigned short* BTn1 = (unsigned short*)(wsb + 65536);
    unsigned short* BTn2 = (unsigned short*)(wsb + 131072);
    unsigned short* BTg0 = (unsigned short*)(wsb + 196608);
    unsigned short* BTg1 = (unsigned short*)(wsb + 229376);
    unsigned short* BTg2 = (unsigned short*)(wsb + 262144);
    unsigned short* BTw_t= (unsigned short*)(wsb + 294912);   // 147456 B tiled
    float* cb   = (float*)(wsb + 442368);
    float* b1c  = (float*)(wsb + 442880);
    float* W2c  = (float*)(wsb + 443648);
    int*   flags= (int*)  (wsb + 444416);
    float* Pd   = (float*)(wsb + 444480);
    float* Qd   = Pd + (size_t)N_NODES * 128;

    static int attr_set = 0;
    if (!attr_set) {
        (void)hipFuncSetAttribute((const void*)edge_kernel,
                                  hipFuncAttributeMaxDynamicSharedMemorySize,
                                  147456);
        attr_set = 1;
    }

    prep_kernel<<<dim3(128), dim3(256), 0, stream>>>(
        node_W, node_b, nbr_W, nbr_b, gud_W, gud_b, enc_W, enc_b,
        vp_W1, vp_b1, vp_W2, pol_W1, pol_b1, pol_W2,
        BTn0, BTn1, BTn2, BTg0, BTg1, BTg2, BTw_t,
        cb, b1c, W2c, flags);

    node_kernel<<<dim3((N_NODES + 63) / 64), dim3(256), 0, stream>>>(
        x, gf, BTn0, BTn1, BTn2, BTg0, BTg1, BTg2, cb, flags, Pd, Qd);

    edge_kernel<<<dim3(EGRID), dim3(512), 147456, stream>>>(
        ei, Pd, Qd, BTw_t, b1c, W2c, vp_b2, pol_b2, flags, out);
}